// Round 1
// baseline (214.447 us; speedup 1.0000x reference)
//
#include <hip/hip_runtime.h>
#include <hip/hip_bf16.h>
#include <math.h>

// Problem constants (fixed by reference setup_inputs)
constexpr int NROWS = 8192;   // B
constexpr int HDIM  = 256;    // H (= K of the GEMM)
constexpr int N2    = 16384;  // 2*B rows of Z
constexpr int BM    = 128;    // tile M = tile N
constexpr int BK    = 64;     // K chunk staged per round

typedef __attribute__((ext_vector_type(4))) float floatx4;
typedef __attribute__((ext_vector_type(8))) short shortx8; // 8 bf16 = 4 VGPRs

__device__ __forceinline__ void async_copy16(const void* gptr, void* lptr) {
    __builtin_amdgcn_global_load_lds(
        (const __attribute__((address_space(1))) unsigned int*)gptr,
        (__attribute__((address_space(3))) unsigned int*)lptr, 16, 0, 0);
}

// ---------------------------------------------------------------------------
// Kernel 1: row L2-normalize x and y -> bf16 Z [2N, H]; pos[i] = cos(x_i,y_i)
// One block per row pair; thread t owns column t.
// ---------------------------------------------------------------------------
__global__ __launch_bounds__(256) void normalize_kernel(
    const float* __restrict__ x, const float* __restrict__ y,
    __hip_bfloat16* __restrict__ Z, float* __restrict__ pos)
{
    const int row = blockIdx.x;   // 0..8191
    const int t   = threadIdx.x;  // 0..255
    const float xv = x[row * HDIM + t];
    const float yv = y[row * HDIM + t];

    float sx = xv * xv, sy = yv * yv, sxy = xv * yv;
    #pragma unroll
    for (int off = 32; off; off >>= 1) {
        sx  += __shfl_down(sx,  off);
        sy  += __shfl_down(sy,  off);
        sxy += __shfl_down(sxy, off);
    }
    __shared__ float sh[3][4];
    const int wave = t >> 6, lane = t & 63;
    if (lane == 0) { sh[0][wave] = sx; sh[1][wave] = sy; sh[2][wave] = sxy; }
    __syncthreads();
    const float tx  = sh[0][0] + sh[0][1] + sh[0][2] + sh[0][3];
    const float ty  = sh[1][0] + sh[1][1] + sh[1][2] + sh[1][3];
    const float txy = sh[2][0] + sh[2][1] + sh[2][2] + sh[2][3];
    const float rx = rsqrtf(tx), ry = rsqrtf(ty);

    Z[(size_t)row * HDIM + t]            = __float2bfloat16(xv * rx);
    Z[(size_t)(row + NROWS) * HDIM + t]  = __float2bfloat16(yv * ry);
    if (t == 0) {
        const float p = txy * rx * ry;
        pos[row]         = p;
        pos[row + NROWS] = p;
    }
}

// ---------------------------------------------------------------------------
// Kernel 2: upper-triangle tiled Z·Z^T with fused exp(2·sim) and row/col sums.
// Block = 256 threads = 4 waves (2x2), each wave owns a 64x64 subtile as a
// 4x4 grid of 16x16x32 bf16 MFMAs. LDS tiles are [128 rows][64 k] bf16 with
// XOR-swizzled 16B chunks (row stride = 128B = exact bank wrap otherwise).
// ---------------------------------------------------------------------------
__global__ __launch_bounds__(256) void simgemm_kernel(
    const __hip_bfloat16* __restrict__ Z, float* __restrict__ rowsum)
{
    const int bj = blockIdx.x;
    const int bi = blockIdx.y;
    if (bi > bj) return;                  // symmetric: upper triangle only
    const bool diag = (bi == bj);

    __shared__ alignas(16) __hip_bfloat16 tA[BM * BK];  // 16 KB
    __shared__ alignas(16) __hip_bfloat16 tB[BM * BK];  // 16 KB
    __shared__ float rs[BM];
    __shared__ float cs[BM];

    const int tid  = threadIdx.x;
    const int wave = tid >> 6;
    const int lane = tid & 63;
    const int wm   = wave & 1;            // wave row (0..1)
    const int wn   = wave >> 1;           // wave col (0..1)
    const int g    = lane >> 4;           // quad  (0..3)
    const int m15  = lane & 15;

    if (tid < BM) { rs[tid] = 0.f; cs[tid] = 0.f; }

    const int rowA0 = bi * BM;
    const int rowB0 = bj * BM;

    floatx4 acc[4][4] = {};

    // staging address pieces (constant across chunks)
    const int st_row  = wave * 32 + (lane >> 3);      // + t*8 below
    const int st_csrc = (lane & 7) ^ ((lane >> 3) & 7); // XOR swizzle source chunk

    #pragma unroll
    for (int ck = 0; ck < HDIM / BK; ++ck) {
        // ---- stage A and B tiles (global -> LDS, 16B per lane) ----
        #pragma unroll
        for (int t = 0; t < 4; ++t) {
            const int r = st_row + t * 8;
            const size_t goff = (size_t)ck * BK + st_csrc * 8;
            async_copy16(Z + (size_t)(rowA0 + r) * HDIM + goff,
                         &tA[(wave * 32 + t * 8) * BK]);
            async_copy16(Z + (size_t)(rowB0 + r) * HDIM + goff,
                         &tB[(wave * 32 + t * 8) * BK]);
        }
        __syncthreads();

        // ---- 2 k-steps of 32 over this BK=64 chunk ----
        #pragma unroll
        for (int s = 0; s < 2; ++s) {
            shortx8 af[4], bfr[4];
            #pragma unroll
            for (int f = 0; f < 4; ++f) {
                const int ra = wm * 64 + f * 16 + m15;
                af[f] = *(const shortx8*)&tA[ra * BK + (((s * 4 + g) ^ (ra & 7)) * 8)];
                const int rb = wn * 64 + f * 16 + m15;
                bfr[f] = *(const shortx8*)&tB[rb * BK + (((s * 4 + g) ^ (rb & 7)) * 8)];
            }
            #pragma unroll
            for (int fm = 0; fm < 4; ++fm)
                #pragma unroll
                for (int fn = 0; fn < 4; ++fn)
                    acc[fm][fn] = __builtin_amdgcn_mfma_f32_16x16x32_bf16(
                        af[fm], bfr[fn], acc[fm][fn], 0, 0, 0);
        }
        __syncthreads();
    }

    // ---- epilogue: e = exp(2*sim), mask diagonal, reduce rows & cols ----
    float rp[4][4];   // [fm][reg] partial row sums (sum over fn at this lane)
    float cp[4];      // [fn]      partial col sums (sum over fm,reg)
    #pragma unroll
    for (int fm = 0; fm < 4; ++fm)
        #pragma unroll
        for (int q = 0; q < 4; ++q) rp[fm][q] = 0.f;
    #pragma unroll
    for (int fn = 0; fn < 4; ++fn) cp[fn] = 0.f;

    #pragma unroll
    for (int fm = 0; fm < 4; ++fm) {
        #pragma unroll
        for (int fn = 0; fn < 4; ++fn) {
            const floatx4 a = acc[fm][fn];
            #pragma unroll
            for (int q = 0; q < 4; ++q) {
                float e = __expf(2.0f * a[q]);   // exp(sim / tau), tau = 0.5
                if (diag) {
                    const int rl = wm * 64 + fm * 16 + g * 4 + q;
                    const int cl = wn * 64 + fn * 16 + m15;
                    if (rl == cl) e = 0.f;       // exclude self-similarity
                }
                rp[fm][q] += e;
                cp[fn]    += e;
            }
        }
    }

    // row sums: reduce across the 16 lanes sharing a quad (same rows)
    #pragma unroll
    for (int mask = 1; mask < 16; mask <<= 1)
        #pragma unroll
        for (int fm = 0; fm < 4; ++fm)
            #pragma unroll
            for (int q = 0; q < 4; ++q)
                rp[fm][q] += __shfl_xor(rp[fm][q], mask);
    if (m15 == 0) {
        #pragma unroll
        for (int fm = 0; fm < 4; ++fm)
            #pragma unroll
            for (int q = 0; q < 4; ++q)
                atomicAdd(&rs[wm * 64 + fm * 16 + g * 4 + q], rp[fm][q]);
    }

    // col sums: reduce across quads (same cols)
    #pragma unroll
    for (int mask = 16; mask < 64; mask <<= 1)
        #pragma unroll
        for (int fn = 0; fn < 4; ++fn)
            cp[fn] += __shfl_xor(cp[fn], mask);
    if (g == 0) {
        #pragma unroll
        for (int fn = 0; fn < 4; ++fn)
            atomicAdd(&cs[wn * 64 + fn * 16 + m15], cp[fn]);
    }

    __syncthreads();
    if (tid < BM) {
        atomicAdd(&rowsum[(size_t)bi * BM + tid], rs[tid]);
        if (!diag)
            atomicAdd(&rowsum[(size_t)bj * BM + tid], cs[tid]);
    }
}

// ---------------------------------------------------------------------------
// Kernel 3: loss = mean( log(rowsum_i) - 2*pos_i )
// ---------------------------------------------------------------------------
__global__ __launch_bounds__(1024) void finalize_kernel(
    const float* __restrict__ rowsum, const float* __restrict__ pos,
    float* __restrict__ out)
{
    const int t = threadIdx.x;
    float s = 0.f;
    for (int i = t; i < N2; i += 1024)
        s += logf(rowsum[i]) - 2.0f * pos[i];
    #pragma unroll
    for (int off = 32; off; off >>= 1) s += __shfl_down(s, off);
    __shared__ float sh[16];
    if ((t & 63) == 0) sh[t >> 6] = s;
    __syncthreads();
    if (t == 0) {
        float tot = 0.f;
        #pragma unroll
        for (int w = 0; w < 16; ++w) tot += sh[w];
        out[0] = tot / (float)N2;
    }
}

// ---------------------------------------------------------------------------
extern "C" void kernel_launch(void* const* d_in, const int* in_sizes, int n_in,
                              void* d_out, int out_size, void* d_ws, size_t ws_size,
                              hipStream_t stream)
{
    const float* x = (const float*)d_in[0];
    const float* y = (const float*)d_in[1];

    // workspace layout: Z bf16 [16384*256] (8 MB) | rowsum f32 [16384] | pos f32 [16384]
    __hip_bfloat16* Z = (__hip_bfloat16*)d_ws;
    float* rowsum = (float*)((char*)d_ws + (size_t)N2 * HDIM * sizeof(__hip_bfloat16));
    float* pos    = rowsum + N2;

    hipMemsetAsync(rowsum, 0, N2 * sizeof(float), stream);
    normalize_kernel<<<NROWS, 256, 0, stream>>>(x, y, Z, pos);
    simgemm_kernel<<<dim3(N2 / BM, N2 / BM), 256, 0, stream>>>(Z, rowsum);
    finalize_kernel<<<1, 1024, 0, stream>>>(rowsum, pos, (float*)d_out);
}

// Round 2
// 198.793 us; speedup vs baseline: 1.0787x; 1.0787x over previous
//
#include <hip/hip_runtime.h>
#include <hip/hip_bf16.h>
#include <math.h>

// Problem constants (fixed by reference setup_inputs)
constexpr int NROWS = 8192;   // B
constexpr int HDIM  = 256;    // H (= K of the GEMM)
constexpr int N2    = 16384;  // 2*B rows of Z
constexpr int BM    = 128;    // tile M = tile N
constexpr int BK    = 64;     // K chunk staged per round

// sqrt(2 * log2(e)): Z is pre-scaled by this so that
// Zs_i . Zs_j = 2*log2(e) * cos_sim  and  exp2(acc) == exp(sim/tau), tau=0.5
constexpr float PRESCALE = 1.69864357f;

typedef __attribute__((ext_vector_type(4))) float floatx4;
typedef __attribute__((ext_vector_type(8))) short shortx8; // 8 bf16 = 4 VGPRs

__device__ __forceinline__ void async_copy16(const void* gptr, void* lptr) {
    __builtin_amdgcn_global_load_lds(
        (const __attribute__((address_space(1))) unsigned int*)gptr,
        (__attribute__((address_space(3))) unsigned int*)lptr, 16, 0, 0);
}

// ---------------------------------------------------------------------------
// Kernel 1: row L2-normalize x and y -> bf16 Z (pre-scaled) [2N, H];
// pos[i] = cos(x_i, y_i) in fp32. Also zeroes rowsum and out (saves a memset
// dispatch; stream order guarantees this lands before simgemm/finalize).
// ---------------------------------------------------------------------------
__global__ __launch_bounds__(256) void normalize_kernel(
    const float* __restrict__ x, const float* __restrict__ y,
    __hip_bfloat16* __restrict__ Z, float* __restrict__ pos,
    float* __restrict__ rowsum, float* __restrict__ out)
{
    const int row = blockIdx.x;   // 0..8191
    const int t   = threadIdx.x;  // 0..255
    const float xv = x[row * HDIM + t];
    const float yv = y[row * HDIM + t];

    float sx = xv * xv, sy = yv * yv, sxy = xv * yv;
    #pragma unroll
    for (int off = 32; off; off >>= 1) {
        sx  += __shfl_down(sx,  off);
        sy  += __shfl_down(sy,  off);
        sxy += __shfl_down(sxy, off);
    }
    __shared__ float sh[3][4];
    const int wave = t >> 6, lane = t & 63;
    if (lane == 0) { sh[0][wave] = sx; sh[1][wave] = sy; sh[2][wave] = sxy; }
    __syncthreads();
    const float tx  = sh[0][0] + sh[0][1] + sh[0][2] + sh[0][3];
    const float ty  = sh[1][0] + sh[1][1] + sh[1][2] + sh[1][3];
    const float txy = sh[2][0] + sh[2][1] + sh[2][2] + sh[2][3];
    const float rx = rsqrtf(tx) * PRESCALE, ry = rsqrtf(ty) * PRESCALE;

    Z[(size_t)row * HDIM + t]            = __float2bfloat16(xv * rx);
    Z[(size_t)(row + NROWS) * HDIM + t]  = __float2bfloat16(yv * ry);
    if (t < 2) rowsum[row * 2 + t] = 0.f;
    if (row == 0 && t == 0) out[0] = 0.f;
    if (t == 0) {
        const float p = txy * rsqrtf(tx) * rsqrtf(ty);
        pos[row]         = p;
        pos[row + NROWS] = p;
    }
}

// ---------------------------------------------------------------------------
// Kernel 2: upper-triangle tiled Z·Z^T with fused exp2 and row/col sums.
// Block = 256 threads = 4 waves (2x2), each wave a 64x64 subtile via 4x4
// grid of 16x16x32 bf16 MFMAs. LDS tiles [128][64] bf16, XOR-swizzled 16B
// chunks (row stride = exact 32-bank wrap otherwise).
// Scheme: every strictly-upper element (gcol > grow globally) is computed
// exactly once and its exp contributes to BOTH rowsum[grow] (row partial)
// and rowsum[gcol] (col partial). Diagonal blocks mask gcol<=grow.
// __launch_bounds__(256,4): cap combined VGPR+AGPR at 128 -> 4 blocks/CU.
// ---------------------------------------------------------------------------
__global__ __launch_bounds__(256, 4) void simgemm_kernel(
    const __hip_bfloat16* __restrict__ Z, float* __restrict__ rowsum)
{
    const int bj = blockIdx.x;
    const int bi = blockIdx.y;
    if (bi > bj) return;                  // symmetric: upper triangle only
    const bool diag = (bi == bj);

    __shared__ alignas(16) __hip_bfloat16 tA[BM * BK];  // 16 KB
    __shared__ alignas(16) __hip_bfloat16 tB[BM * BK];  // 16 KB
    __shared__ float rs[BM];
    __shared__ float cs[BM];

    const int tid  = threadIdx.x;
    const int wave = tid >> 6;
    const int lane = tid & 63;
    const int wm   = wave & 1;            // wave row (0..1)
    const int wn   = wave >> 1;           // wave col (0..1)
    const int g    = lane >> 4;           // quad  (0..3)
    const int m15  = lane & 15;

    if (tid < BM) { rs[tid] = 0.f; cs[tid] = 0.f; }

    const int rowA0 = bi * BM;
    const int rowB0 = bj * BM;

    floatx4 acc[4][4] = {};

    // staging address pieces (constant across chunks)
    const int st_row  = wave * 32 + (lane >> 3);        // + t*8 below
    const int st_csrc = (lane & 7) ^ ((lane >> 3) & 7); // XOR swizzle source chunk

    #pragma unroll
    for (int ck = 0; ck < HDIM / BK; ++ck) {
        // ---- stage A and B tiles (global -> LDS, 16B per lane) ----
        #pragma unroll
        for (int t = 0; t < 4; ++t) {
            const int r = st_row + t * 8;
            const size_t goff = (size_t)ck * BK + st_csrc * 8;
            async_copy16(Z + (size_t)(rowA0 + r) * HDIM + goff,
                         &tA[(wave * 32 + t * 8) * BK]);
            async_copy16(Z + (size_t)(rowB0 + r) * HDIM + goff,
                         &tB[(wave * 32 + t * 8) * BK]);
        }
        __syncthreads();

        // ---- 2 k-steps of 32 over this BK=64 chunk ----
        #pragma unroll
        for (int s = 0; s < 2; ++s) {
            shortx8 af[4], bfr[4];
            #pragma unroll
            for (int f = 0; f < 4; ++f) {
                const int ra = wm * 64 + f * 16 + m15;
                af[f] = *(const shortx8*)&tA[ra * BK + (((s * 4 + g) ^ (ra & 7)) * 8)];
                const int rb = wn * 64 + f * 16 + m15;
                bfr[f] = *(const shortx8*)&tB[rb * BK + (((s * 4 + g) ^ (rb & 7)) * 8)];
            }
            #pragma unroll
            for (int fm = 0; fm < 4; ++fm)
                #pragma unroll
                for (int fn = 0; fn < 4; ++fn)
                    acc[fm][fn] = __builtin_amdgcn_mfma_f32_16x16x32_bf16(
                        af[fm], bfr[fn], acc[fm][fn], 0, 0, 0);
        }
        __syncthreads();
    }

    // ---- epilogue: e = exp2(acc) (== exp(sim/tau)), reduce rows & cols ----
    float rp[4][4] = {{0.f}};  // [fm][reg] partial row sums
    float cp[4]    = {0.f};    // [fn]      partial col sums

    if (!diag) {
        #pragma unroll
        for (int fm = 0; fm < 4; ++fm)
            #pragma unroll
            for (int fn = 0; fn < 4; ++fn) {
                const floatx4 a = acc[fm][fn];
                #pragma unroll
                for (int q = 0; q < 4; ++q) {
                    const float e = __builtin_amdgcn_exp2f(a[q]);
                    rp[fm][q] += e;
                    cp[fn]    += e;
                }
            }
    } else {
        #pragma unroll
        for (int fm = 0; fm < 4; ++fm)
            #pragma unroll
            for (int fn = 0; fn < 4; ++fn) {
                const floatx4 a = acc[fm][fn];
                const int cl = wn * 64 + fn * 16 + m15;
                #pragma unroll
                for (int q = 0; q < 4; ++q) {
                    const int rl = wm * 64 + fm * 16 + g * 4 + q;
                    float e = __builtin_amdgcn_exp2f(a[q]);
                    if (cl <= rl) e = 0.f;   // keep strictly-upper only
                    rp[fm][q] += e;
                    cp[fn]    += e;
                }
            }
    }

    // row sums: reduce across the 16 lanes sharing a quad (same rows)
    #pragma unroll
    for (int mask = 1; mask < 16; mask <<= 1)
        #pragma unroll
        for (int fm = 0; fm < 4; ++fm)
            #pragma unroll
            for (int q = 0; q < 4; ++q)
                rp[fm][q] += __shfl_xor(rp[fm][q], mask);
    if (m15 == 0) {
        #pragma unroll
        for (int fm = 0; fm < 4; ++fm)
            #pragma unroll
            for (int q = 0; q < 4; ++q)
                atomicAdd(&rs[wm * 64 + fm * 16 + g * 4 + q], rp[fm][q]);
    }

    // col sums: reduce across quads (same cols)
    #pragma unroll
    for (int mask = 16; mask < 64; mask <<= 1)
        #pragma unroll
        for (int fn = 0; fn < 4; ++fn)
            cp[fn] += __shfl_xor(cp[fn], mask);
    if (g == 0) {
        #pragma unroll
        for (int fn = 0; fn < 4; ++fn)
            atomicAdd(&cs[wn * 64 + fn * 16 + m15], cp[fn]);
    }

    __syncthreads();
    if (tid < BM) {
        atomicAdd(&rowsum[(size_t)bi * BM + tid], rs[tid]);
        atomicAdd(&rowsum[(size_t)bj * BM + tid], cs[tid]);
    }
}

// ---------------------------------------------------------------------------
// Kernel 3: loss = mean( log(rowsum_i) - 2*pos_i ), 8 blocks + atomic.
// out[0] was zeroed by normalize_kernel (stream-ordered before this).
// ---------------------------------------------------------------------------
__global__ __launch_bounds__(1024) void finalize_kernel(
    const float* __restrict__ rowsum, const float* __restrict__ pos,
    float* __restrict__ out)
{
    const int t = threadIdx.x + blockIdx.x * 1024;
    float s = 0.f;
    for (int i = t; i < N2; i += 8192)
        s += logf(rowsum[i]) - 2.0f * pos[i];
    #pragma unroll
    for (int off = 32; off; off >>= 1) s += __shfl_down(s, off);
    __shared__ float sh[16];
    const int lt = threadIdx.x;
    if ((lt & 63) == 0) sh[lt >> 6] = s;
    __syncthreads();
    if (lt == 0) {
        float tot = 0.f;
        #pragma unroll
        for (int w = 0; w < 16; ++w) tot += sh[w];
        atomicAdd(out, tot / (float)N2);
    }
}

// ---------------------------------------------------------------------------
extern "C" void kernel_launch(void* const* d_in, const int* in_sizes, int n_in,
                              void* d_out, int out_size, void* d_ws, size_t ws_size,
                              hipStream_t stream)
{
    const float* x = (const float*)d_in[0];
    const float* y = (const float*)d_in[1];

    // workspace layout: Z bf16 [16384*256] (8 MB) | rowsum f32 [16384] | pos f32 [16384]
    __hip_bfloat16* Z = (__hip_bfloat16*)d_ws;
    float* rowsum = (float*)((char*)d_ws + (size_t)N2 * HDIM * sizeof(__hip_bfloat16));
    float* pos    = rowsum + N2;

    normalize_kernel<<<NROWS, 256, 0, stream>>>(x, y, Z, pos, rowsum, (float*)d_out);
    simgemm_kernel<<<dim3(N2 / BM, N2 / BM), 256, 0, stream>>>(Z, rowsum);
    finalize_kernel<<<8, 1024, 0, stream>>>(rowsum, pos, (float*)d_out);
}

// Round 3
// 194.990 us; speedup vs baseline: 1.0998x; 1.0195x over previous
//
#include <hip/hip_runtime.h>
#include <hip/hip_bf16.h>
#include <math.h>

// Problem constants (fixed by reference setup_inputs)
constexpr int NROWS = 8192;   // B
constexpr int HDIM  = 256;    // H (= K of the GEMM)
constexpr int N2    = 16384;  // 2*B rows of Z
constexpr int BM    = 128;    // tile M = tile N
constexpr int BK    = 64;     // K chunk staged per round
constexpr int NTILE = N2 / BM;        // 128 tile-rows
constexpr int NBLK  = NTILE * (NTILE + 1) / 2;  // 8256 upper-tri tiles

// sqrt(2 * log2(e)): Z pre-scaled so Zs_i.Zs_j = 2*log2(e)*cos and
// exp2(acc) == exp(sim/tau), tau = 0.5
constexpr float PRESCALE = 1.69864357f;

typedef __attribute__((ext_vector_type(4))) float floatx4;
typedef __attribute__((ext_vector_type(8))) short shortx8; // 8 bf16 = 4 VGPRs

__device__ __forceinline__ void async_copy16(const void* gptr, void* lptr) {
    __builtin_amdgcn_global_load_lds(
        (const __attribute__((address_space(1))) unsigned int*)gptr,
        (__attribute__((address_space(3))) unsigned int*)lptr, 16, 0, 0);
}

// s_waitcnt immediates (gfx9 encoding: vm[3:0]|exp[6:4]|lgkm[11:8]|vm[15:14])
#define WAIT_VM8()   __builtin_amdgcn_s_waitcnt(0x0F78)  // vmcnt(8), others free
#define WAIT_VM0()   __builtin_amdgcn_s_waitcnt(0x0F70)  // vmcnt(0), others free
#define WAIT_LGKM0() __builtin_amdgcn_s_waitcnt(0xC07F)  // lgkmcnt(0), vm free
#define MEMFENCE()   __asm__ __volatile__("" ::: "memory")
#define RAW_BARRIER() do { MEMFENCE(); __builtin_amdgcn_s_barrier(); MEMFENCE(); } while (0)

// ---------------------------------------------------------------------------
// Kernel 1: wave-per-row L2-normalize -> bf16 Z (pre-scaled); pos = cos(x,y).
// 64 lanes x float4 per row, xor-shuffle reduce, 8B vector bf16 stores.
// Also zeroes rowsum and out (stream-ordered before consumers).
// ---------------------------------------------------------------------------
__global__ __launch_bounds__(256) void normalize_kernel(
    const float* __restrict__ x, const float* __restrict__ y,
    __hip_bfloat16* __restrict__ Z, float* __restrict__ pos,
    float* __restrict__ rowsum, float* __restrict__ out)
{
    const int wave = threadIdx.x >> 6, lane = threadIdx.x & 63;
    const int row  = blockIdx.x * 4 + wave;           // grid 2048 -> 8192 rows

    const float4 xv = ((const float4*)x)[row * 64 + lane];
    const float4 yv = ((const float4*)y)[row * 64 + lane];

    float sx  = xv.x*xv.x + xv.y*xv.y + xv.z*xv.z + xv.w*xv.w;
    float sy  = yv.x*yv.x + yv.y*yv.y + yv.z*yv.z + yv.w*yv.w;
    float sxy = xv.x*yv.x + xv.y*yv.y + xv.z*yv.z + xv.w*yv.w;
    #pragma unroll
    for (int m = 1; m < 64; m <<= 1) {
        sx  += __shfl_xor(sx,  m);
        sy  += __shfl_xor(sy,  m);
        sxy += __shfl_xor(sxy, m);
    }
    const float rxn = rsqrtf(sx), ryn = rsqrtf(sy);
    const float rx = rxn * PRESCALE, ry = ryn * PRESCALE;

    union { ushort4 u; __hip_bfloat16 h[4]; } zx, zy;
    zx.h[0] = __float2bfloat16(xv.x * rx); zx.h[1] = __float2bfloat16(xv.y * rx);
    zx.h[2] = __float2bfloat16(xv.z * rx); zx.h[3] = __float2bfloat16(xv.w * rx);
    zy.h[0] = __float2bfloat16(yv.x * ry); zy.h[1] = __float2bfloat16(yv.y * ry);
    zy.h[2] = __float2bfloat16(yv.z * ry); zy.h[3] = __float2bfloat16(yv.w * ry);
    ((ushort4*)Z)[row * 64 + lane]             = zx.u;
    ((ushort4*)Z)[(row + NROWS) * 64 + lane]   = zy.u;

    if (lane == 0) {
        const float p = sxy * rxn * ryn;
        pos[row]         = p;
        pos[row + NROWS] = p;
    }
    const int gt = blockIdx.x * 256 + threadIdx.x;
    if (gt < N2) rowsum[gt] = 0.f;
    if (gt == 0) out[0] = 0.f;
}

// ---------------------------------------------------------------------------
// Kernel 2: upper-triangle tiled Z·Z^T, fused exp2 + row/col sums.
// 1D triangular grid (no dead blocks). Double-buffered LDS staging with RAW
// s_barrier + manual vmcnt(8): the next chunk's 8 global_load_lds stay in
// flight across the barrier (compiler __syncthreads would drain vmcnt(0) —
// the R2 137us stall). Pipeline per iter ck:
//   issue ck+1 -> buf[(ck+1)&1]; wait vmcnt(8); barrier;    (ck data landed)
//   MFMA from buf[ck&1]; wait lgkmcnt(0); barrier;          (WAR-safe reuse)
// ---------------------------------------------------------------------------
__global__ __launch_bounds__(256, 2) void simgemm_kernel(
    const __hip_bfloat16* __restrict__ Z, float* __restrict__ rowsum)
{
    // linear -> (bi, bj) upper-triangle mapping; cum(bi) = bi*(257-bi)/2
    const int b = blockIdx.x;
    int bi = (int)((257.0 - sqrt(66049.0 - 8.0 * (double)b)) * 0.5);
    int cum = bi * (257 - bi) / 2;
    if (b < cum)      { bi--; cum = bi * (257 - bi) / 2; }
    else { const int cn = (bi + 1) * (256 - bi) / 2;
           if (b >= cn) { bi++; cum = cn; } }
    const int bj = bi + (b - cum);
    const bool diag = (bi == bj);

    __shared__ alignas(16) __hip_bfloat16 tA[2][BM * BK];  // 2 x 16 KB
    __shared__ alignas(16) __hip_bfloat16 tB[2][BM * BK];  // 2 x 16 KB
    __shared__ float rs[BM];
    __shared__ float cs[BM];

    const int tid  = threadIdx.x;
    const int wave = tid >> 6;
    const int lane = tid & 63;
    const int wm   = wave & 1;            // wave row (0..1)
    const int wn   = wave >> 1;           // wave col (0..1)
    const int g    = lane >> 4;           // quad  (0..3)
    const int m15  = lane & 15;

    if (tid < BM) { rs[tid] = 0.f; cs[tid] = 0.f; }

    const int rowA0 = bi * BM;
    const int rowB0 = bj * BM;

    floatx4 acc[4][4] = {};

    // staging address pieces (constant across chunks)
    const int st_row  = wave * 32 + (lane >> 3);        // + t*8 below
    const int st_csrc = (lane & 7) ^ ((lane >> 3) & 7); // XOR swizzle src chunk

    // issue one chunk's 8 loads (per wave) into buffer `buf`
    auto stage = [&](int ck, int buf) {
        #pragma unroll
        for (int t = 0; t < 4; ++t) {
            const int r = st_row + t * 8;
            const size_t goff = (size_t)ck * BK + st_csrc * 8;
            async_copy16(Z + (size_t)(rowA0 + r) * HDIM + goff,
                         &tA[buf][(wave * 32 + t * 8) * BK]);
            async_copy16(Z + (size_t)(rowB0 + r) * HDIM + goff,
                         &tB[buf][(wave * 32 + t * 8) * BK]);
        }
    };

    stage(0, 0);   // prologue

    #pragma unroll
    for (int ck = 0; ck < HDIM / BK; ++ck) {
        const int cur = ck & 1;
        if (ck + 1 < HDIM / BK) stage(ck + 1, cur ^ 1);
        if (ck + 1 < HDIM / BK) WAIT_VM8(); else WAIT_VM0();
        RAW_BARRIER();

        #pragma unroll
        for (int s = 0; s < 2; ++s) {
            shortx8 af[4], bfr[4];
            #pragma unroll
            for (int f = 0; f < 4; ++f) {
                const int ra = wm * 64 + f * 16 + m15;
                af[f]  = *(const shortx8*)&tA[cur][ra * BK + (((s * 4 + g) ^ (ra & 7)) * 8)];
                const int rb = wn * 64 + f * 16 + m15;
                bfr[f] = *(const shortx8*)&tB[cur][rb * BK + (((s * 4 + g) ^ (rb & 7)) * 8)];
            }
            #pragma unroll
            for (int fm = 0; fm < 4; ++fm)
                #pragma unroll
                for (int fn = 0; fn < 4; ++fn)
                    acc[fm][fn] = __builtin_amdgcn_mfma_f32_16x16x32_bf16(
                        af[fm], bfr[fn], acc[fm][fn], 0, 0, 0);
        }
        WAIT_LGKM0();    // all ds_reads of this buffer complete
        RAW_BARRIER();   // before any wave overwrites it next iteration
    }

    // ---- epilogue: e = exp2(acc) (== exp(sim/tau)), reduce rows & cols ----
    float rp[4][4] = {{0.f}};  // [fm][reg] partial row sums
    float cp[4]    = {0.f};    // [fn]      partial col sums

    if (!diag) {
        #pragma unroll
        for (int fm = 0; fm < 4; ++fm)
            #pragma unroll
            for (int fn = 0; fn < 4; ++fn) {
                const floatx4 a = acc[fm][fn];
                #pragma unroll
                for (int q = 0; q < 4; ++q) {
                    const float e = __builtin_amdgcn_exp2f(a[q]);
                    rp[fm][q] += e;
                    cp[fn]    += e;
                }
            }
    } else {
        #pragma unroll
        for (int fm = 0; fm < 4; ++fm)
            #pragma unroll
            for (int fn = 0; fn < 4; ++fn) {
                const floatx4 a = acc[fm][fn];
                const int cl = wn * 64 + fn * 16 + m15;
                #pragma unroll
                for (int q = 0; q < 4; ++q) {
                    const int rl = wm * 64 + fm * 16 + g * 4 + q;
                    float e = __builtin_amdgcn_exp2f(a[q]);
                    if (cl <= rl) e = 0.f;   // strictly-upper only
                    rp[fm][q] += e;
                    cp[fn]    += e;
                }
            }
    }

    // row sums: reduce across the 16 lanes sharing a quad (same rows)
    #pragma unroll
    for (int mask = 1; mask < 16; mask <<= 1)
        #pragma unroll
        for (int fm = 0; fm < 4; ++fm)
            #pragma unroll
            for (int q = 0; q < 4; ++q)
                rp[fm][q] += __shfl_xor(rp[fm][q], mask);
    if (m15 == 0) {
        #pragma unroll
        for (int fm = 0; fm < 4; ++fm)
            #pragma unroll
            for (int q = 0; q < 4; ++q)
                atomicAdd(&rs[wm * 64 + fm * 16 + g * 4 + q], rp[fm][q]);
    }

    // col sums: reduce across quads (same cols)
    #pragma unroll
    for (int mask = 16; mask < 64; mask <<= 1)
        #pragma unroll
        for (int fn = 0; fn < 4; ++fn)
            cp[fn] += __shfl_xor(cp[fn], mask);
    if (g == 0) {
        #pragma unroll
        for (int fn = 0; fn < 4; ++fn)
            atomicAdd(&cs[wn * 64 + fn * 16 + m15], cp[fn]);
    }

    __syncthreads();
    if (tid < BM) {
        atomicAdd(&rowsum[(size_t)bi * BM + tid], rs[tid]);
        atomicAdd(&rowsum[(size_t)bj * BM + tid], cs[tid]);
    }
}

// ---------------------------------------------------------------------------
// Kernel 3: loss = mean( log(rowsum_i) - 2*pos_i ), 16 blocks + atomic.
// out[0] zeroed by normalize_kernel (stream-ordered).
// ---------------------------------------------------------------------------
__global__ __launch_bounds__(1024) void finalize_kernel(
    const float* __restrict__ rowsum, const float* __restrict__ pos,
    float* __restrict__ out)
{
    const int i = threadIdx.x + blockIdx.x * 1024;
    float s = logf(rowsum[i]) - 2.0f * pos[i];
    #pragma unroll
    for (int off = 32; off; off >>= 1) s += __shfl_down(s, off);
    __shared__ float sh[16];
    const int lt = threadIdx.x;
    if ((lt & 63) == 0) sh[lt >> 6] = s;
    __syncthreads();
    if (lt == 0) {
        float tot = 0.f;
        #pragma unroll
        for (int w = 0; w < 16; ++w) tot += sh[w];
        atomicAdd(out, tot / (float)N2);
    }
}

// ---------------------------------------------------------------------------
extern "C" void kernel_launch(void* const* d_in, const int* in_sizes, int n_in,
                              void* d_out, int out_size, void* d_ws, size_t ws_size,
                              hipStream_t stream)
{
    const float* x = (const float*)d_in[0];
    const float* y = (const float*)d_in[1];

    // workspace: Z bf16 [16384*256] (8 MB) | rowsum f32 [16384] | pos f32 [16384]
    __hip_bfloat16* Z = (__hip_bfloat16*)d_ws;
    float* rowsum = (float*)((char*)d_ws + (size_t)N2 * HDIM * sizeof(__hip_bfloat16));
    float* pos    = rowsum + N2;

    normalize_kernel<<<NROWS / 4, 256, 0, stream>>>(x, y, Z, pos, rowsum, (float*)d_out);
    simgemm_kernel<<<NBLK, 256, 0, stream>>>(Z, rowsum);
    finalize_kernel<<<N2 / 1024, 1024, 0, stream>>>(rowsum, pos, (float*)d_out);
}